// Round 11
// baseline (4582.446 us; speedup 1.0000x reference)
//
#include <hip/hip_runtime.h>
#include <math.h>

typedef __attribute__((ext_vector_type(8))) short bf16x8;
typedef __attribute__((ext_vector_type(4))) float f32x4;

__device__ __forceinline__ unsigned short f2bf(float x) {
    unsigned int u = __float_as_uint(x);
    u += 0x7fffu + ((u >> 16) & 1u);
    return (unsigned short)(u >> 16);
}
__device__ __forceinline__ float bf2f(unsigned short b) {
    return __uint_as_float(((unsigned int)b) << 16);
}
// fast activations: v_exp_f32 + v_rcp_f32 (rel err ~1e-7, far below bf16 noise)
__device__ __forceinline__ float fsig(float z) {
    float e = __expf(-z);
    return __builtin_amdgcn_rcpf(1.f + e);
}
// tanh(x) = 2*sigmoid(2x) - 1
__device__ __forceinline__ float ftanh(float x) {
    float e = __expf(-2.f * x);
    float s = __builtin_amdgcn_rcpf(1.f + e);
    return fmaf(2.f, s, -1.f);
}
__device__ __forceinline__ bf16x8 pack8(float4 a, float4 b) {
    bf16x8 r;
    r[0] = (short)f2bf(a.x); r[1] = (short)f2bf(a.y);
    r[2] = (short)f2bf(a.z); r[3] = (short)f2bf(a.w);
    r[4] = (short)f2bf(b.x); r[5] = (short)f2bf(b.y);
    r[6] = (short)f2bf(b.z); r[7] = (short)f2bf(b.w);
    return r;
}

// ---------------------------------------------------------------------------
// prep: convert Wih and Whh to bf16, bias sums
// ---------------------------------------------------------------------------
__global__ void prep_kernel(const float* __restrict__ Wf_ih, const float* __restrict__ Wb_ih,
                            const float* __restrict__ Wf_hh, const float* __restrict__ Wb_hh,
                            const float* __restrict__ bf_ih, const float* __restrict__ bf_hh,
                            const float* __restrict__ bb_ih, const float* __restrict__ bb_hh,
                            unsigned short* __restrict__ wihbf,
                            unsigned short* __restrict__ whhbf,
                            float* __restrict__ biasz) {
    int i = blockIdx.x * 256 + threadIdx.x;   // grid 512*256 = 131072
    if (i < 131072) {
        wihbf[i]          = f2bf(Wf_ih[i]);
        wihbf[131072 + i] = f2bf(Wb_ih[i]);
    }
    if (i < 65536) {
        whhbf[i]         = f2bf(Wf_hh[i]);
        whhbf[65536 + i] = f2bf(Wb_hh[i]);
    }
    if (i < 512) {
        biasz[i]       = bf_ih[i] + bf_hh[i];
        biasz[512 + i] = bb_ih[i] + bb_hh[i];
    }
}

// ---------------------------------------------------------------------------
// generic fp32 GEMM  C[M,N] = A[M,K] @ B[K,N] + bias ; flags: 1=relu_out 2=relu_A
// ---------------------------------------------------------------------------
__global__ __launch_bounds__(256) void gemm64(const float* __restrict__ A,
                                              const float* __restrict__ Bm,
                                              const float* __restrict__ bias,
                                              float* __restrict__ C,
                                              int M, int N, int K, int flags) {
    __shared__ float As[16][68];
    __shared__ float Bs[16][68];
    const int t = threadIdx.x;
    const int row0 = blockIdx.y * 64, col0 = blockIdx.x * 64;
    const int tm = t >> 4, tn = t & 15;
    float acc[4][4] = {};
    for (int k0 = 0; k0 < K; k0 += 16) {
        {
            int r = t >> 2, kq = (t & 3) * 4;
            float4 v = *(const float4*)(A + (size_t)(row0 + r) * K + k0 + kq);
            if (flags & 2) {
                v.x = fmaxf(v.x, 0.f); v.y = fmaxf(v.y, 0.f);
                v.z = fmaxf(v.z, 0.f); v.w = fmaxf(v.w, 0.f);
            }
            As[kq + 0][r] = v.x; As[kq + 1][r] = v.y;
            As[kq + 2][r] = v.z; As[kq + 3][r] = v.w;
        }
        {
            int kk = t >> 4, nq = (t & 15) * 4;
            float4 v = *(const float4*)(Bm + (size_t)(k0 + kk) * N + col0 + nq);
            *(float4*)&Bs[kk][nq] = v;
        }
        __syncthreads();
#pragma unroll
        for (int kk = 0; kk < 16; ++kk) {
            float a[4], b[4];
#pragma unroll
            for (int i = 0; i < 4; ++i) a[i] = As[kk][tm * 4 + i];
#pragma unroll
            for (int j = 0; j < 4; ++j) b[j] = Bs[kk][tn * 4 + j];
#pragma unroll
            for (int i = 0; i < 4; ++i)
#pragma unroll
                for (int j = 0; j < 4; ++j) acc[i][j] = fmaf(a[i], b[j], acc[i][j]);
        }
        __syncthreads();
    }
#pragma unroll
    for (int i = 0; i < 4; ++i) {
#pragma unroll
        for (int j = 0; j < 4; ++j) {
            int col = col0 + tn * 4 + j;
            float v = acc[i][j] + (bias ? bias[col] : 0.f);
            if (flags & 1) v = fmaxf(v, 0.f);
            C[(size_t)(row0 + tm * 4 + i) * N + col] = v;
        }
    }
}

// ---------------------------------------------------------------------------
// LayerNorm over 256, one wave per row. Optional relu, optional dup output.
// ---------------------------------------------------------------------------
__global__ __launch_bounds__(256) void ln256_kernel(const float* __restrict__ X,
                                                    float* __restrict__ Y,
                                                    float* __restrict__ Y2,
                                                    const float* __restrict__ gam,
                                                    const float* __restrict__ bet,
                                                    int relu) {
#pragma clang fp contract(off)
    int row = blockIdx.x * 4 + (threadIdx.x >> 6);
    int l = threadIdx.x & 63;
    float4 x = *(const float4*)(X + (size_t)row * 256 + l * 4);
    float s = x.x + x.y + x.z + x.w;
#pragma unroll
    for (int d = 1; d < 64; d <<= 1) s += __shfl_xor(s, d);
    float mu = s * (1.f / 256.f);
    float d0 = x.x - mu, d1 = x.y - mu, d2 = x.z - mu, d3 = x.w - mu;
    float ss = d0 * d0 + d1 * d1 + d2 * d2 + d3 * d3;
#pragma unroll
    for (int d = 1; d < 64; d <<= 1) ss += __shfl_xor(ss, d);
    float var = ss * (1.f / 256.f);
    float sd = sqrtf(var + 1e-5f);
    float4 y;
    y.x = (d0 / sd) * gam[l * 4 + 0] + bet[l * 4 + 0];
    y.y = (d1 / sd) * gam[l * 4 + 1] + bet[l * 4 + 1];
    y.z = (d2 / sd) * gam[l * 4 + 2] + bet[l * 4 + 2];
    y.w = (d3 / sd) * gam[l * 4 + 3] + bet[l * 4 + 3];
    if (relu) {
        y.x = fmaxf(y.x, 0.f); y.y = fmaxf(y.y, 0.f);
        y.z = fmaxf(y.z, 0.f); y.w = fmaxf(y.w, 0.f);
    }
    *(float4*)(Y + (size_t)row * 256 + l * 4) = y;
    if (Y2) *(float4*)(Y2 + (size_t)row * 256 + l * 4) = y;
}

// LayerNorm over 64 + tanh, one wave per row
__global__ __launch_bounds__(256) void ln64_tanh_kernel(const float* __restrict__ X,
                                                        float* __restrict__ Y,
                                                        const float* __restrict__ gam,
                                                        const float* __restrict__ bet) {
#pragma clang fp contract(off)
    int row = blockIdx.x * 4 + (threadIdx.x >> 6);
    int l = threadIdx.x & 63;
    float x = X[(size_t)row * 64 + l];
    float s = x;
#pragma unroll
    for (int d = 1; d < 64; d <<= 1) s += __shfl_xor(s, d);
    float mu = s * (1.f / 64.f);
    float dx = x - mu;
    float ss = dx * dx;
#pragma unroll
    for (int d = 1; d < 64; d <<= 1) ss += __shfl_xor(ss, d);
    float var = ss * (1.f / 64.f);
    float sd = sqrtf(var + 1e-5f);
    float y = tanhf((dx / sd) * gam[l] + bet[l]);
    Y[(size_t)row * 64 + l] = y;
}

// ---------------------------------------------------------------------------
// attention head: p = sigmoid(a2 @ Wa3 + ba3), flags = p > 0.4
// ---------------------------------------------------------------------------
__global__ __launch_bounds__(256) void attn_head_kernel(const float* __restrict__ a2,
                                                        const float* __restrict__ Wa3,
                                                        const float* __restrict__ ba3,
                                                        float* __restrict__ outP,
                                                        float* __restrict__ outInit,
                                                        int* __restrict__ flags) {
#pragma clang fp contract(off)
    int row = blockIdx.x * 4 + (threadIdx.x >> 6);
    int l = threadIdx.x & 63;
    float s = a2[(size_t)row * 128 + l] * Wa3[l] + a2[(size_t)row * 128 + 64 + l] * Wa3[64 + l];
#pragma unroll
    for (int d = 1; d < 64; d <<= 1) s += __shfl_xor(s, d);
    s += ba3[0];
    float p = 1.f / (1.f + expf(-s));
    if (l == 0) {
        outP[row] = p;
        int f = (p > 0.4f) ? 1 : 0;
        outInit[row] = f ? 1.f : 0.f;
        flags[row] = f;
    }
}

// ---------------------------------------------------------------------------
// batched dot: dot[b] = th_b @ th_b^T   (128x128, K=256); 2 blocks per batch
// ---------------------------------------------------------------------------
__global__ __launch_bounds__(256) void dot_kernel(const float* __restrict__ th,
                                                  float* __restrict__ dotm) {
    __shared__ float As[16][68];
    __shared__ float Bs[16][132];
    const int b = blockIdx.x >> 1, half = blockIdx.x & 1;
    const int t = threadIdx.x;
    const int tm = t >> 4, tn = t & 15;
    float acc[4][8] = {};
    const float* base = th + (size_t)b * 128 * 256;
    for (int k0 = 0; k0 < 256; k0 += 16) {
        {
            int r = t >> 2, kq = (t & 3) * 4;
            float4 v = *(const float4*)(base + (size_t)(half * 64 + r) * 256 + k0 + kq);
            As[kq + 0][r] = v.x; As[kq + 1][r] = v.y;
            As[kq + 2][r] = v.z; As[kq + 3][r] = v.w;
        }
        {
            int n = t >> 1, kq = (t & 1) * 8;
            const float* src = base + (size_t)n * 256 + k0 + kq;
            float4 v0 = *(const float4*)src;
            float4 v1 = *(const float4*)(src + 4);
            Bs[kq + 0][n] = v0.x; Bs[kq + 1][n] = v0.y;
            Bs[kq + 2][n] = v0.z; Bs[kq + 3][n] = v0.w;
            Bs[kq + 4][n] = v1.x; Bs[kq + 5][n] = v1.y;
            Bs[kq + 6][n] = v1.z; Bs[kq + 7][n] = v1.w;
        }
        __syncthreads();
#pragma unroll
        for (int kk = 0; kk < 16; ++kk) {
            float a[4], bb[8];
#pragma unroll
            for (int i = 0; i < 4; ++i) a[i] = As[kk][tm * 4 + i];
#pragma unroll
            for (int j = 0; j < 8; ++j) bb[j] = Bs[kk][tn * 8 + j];
#pragma unroll
            for (int i = 0; i < 4; ++i)
#pragma unroll
                for (int j = 0; j < 8; ++j) acc[i][j] = fmaf(a[i], bb[j], acc[i][j]);
        }
        __syncthreads();
    }
#pragma unroll
    for (int i = 0; i < 4; ++i)
#pragma unroll
        for (int j = 0; j < 8; ++j)
            dotm[(size_t)b * 16384 + (size_t)(half * 64 + tm * 4 + i) * 128 + tn * 8 + j] = acc[i][j];
}

__global__ void sq_kernel(const float* __restrict__ dotm, float* __restrict__ sq) {
    int i = blockIdx.x * 256 + threadIdx.x;   // 64 blocks
    int b = i >> 7, n = i & 127;
    sq[i] = dotm[(size_t)b * 16384 + (size_t)n * 129];
}

// ---------------------------------------------------------------------------
// top-16 smallest distances per row (ties -> lower index), write C + idx
// ---------------------------------------------------------------------------
__global__ __launch_bounds__(256) void topk_kernel(const float* __restrict__ dotm,
                                                   const float* __restrict__ sq,
                                                   const int* __restrict__ flags,
                                                   float* __restrict__ outC,
                                                   int* __restrict__ idxb) {
#pragma clang fp contract(off)
    int row = blockIdx.x * 4 + (threadIdx.x >> 6);
    int l = threadIdx.x & 63;
    int b = row >> 7;
    const float* drow = dotm + (size_t)row * 128;
    float sqi = sq[row];
    float t0 = 2.f * drow[l];
    float v0 = sq[b * 128 + l] - t0; v0 = v0 + sqi;
    float t1 = 2.f * drow[64 + l];
    float v1 = sq[b * 128 + 64 + l] - t1; v1 = v1 + sqi;

    unsigned long long mlo = 0ull, mhi = 0ull;
#pragma unroll 1
    for (int n = 0; n < 16; ++n) {
        float bv = v0; int bi = l;
        if (v1 < bv) { bv = v1; bi = 64 + l; }
#pragma unroll
        for (int d = 1; d < 64; d <<= 1) {
            float ov = __shfl_xor(bv, d);
            int oi = __shfl_xor(bi, d);
            if (ov < bv || (ov == bv && oi < bi)) { bv = ov; bi = oi; }
        }
        if (bi < 64) mlo |= (1ull << bi); else mhi |= (1ull << (bi - 64));
        if (l == bi) v0 = __builtin_inff();
        if (64 + l == bi) v1 = __builtin_inff();
    }
    float fl = (flags[row] != 0) ? 1.f : 0.f;
    outC[(size_t)row * 128 + l]      = fl * (((mlo >> l) & 1ull) ? 1.f : 0.f);
    outC[(size_t)row * 128 + 64 + l] = fl * (((mhi >> l) & 1ull) ? 1.f : 0.f);
    if (l < 16) {
        int cnt = 0, found = -1;
        for (int jj = 0; jj < 128; ++jj) {
            bool bit = (jj < 64) ? ((mlo >> jj) & 1ull) : ((mhi >> (jj - 64)) & 1ull);
            if (bit) { if (cnt == l) { found = jj; break; } ++cnt; }
        }
        idxb[(size_t)row * 16 + l] = found;
    }
}

// ---------------------------------------------------------------------------
// THE CHAIN: one 256-thread block per batch, 4 waves (2 fwd, 2 bwd),
// __launch_bounds__(256,1) -> 1 wave/SIMD -> 512-VGPR budget. Wave (dir,ww)
// owns 64 hidden units {ww*64 + q*16 + lr, q=0..3}; Whh resident as 64
// bf16x8 fragments = 256 regs (legal under the 512 cap — the spill-free
// version of R9's idea). Per step: 4x ds_read_b128 (h) + 64 MFMA (no
// competing wave on the SIMD) + acts for 4 units/lane + 1 ds_write_b16 per
// lane (lane (lg,lr) writes unit lg*16+lr) + ONE 4-wave barrier.
// h history in hsnap[2][18][128] with permanent zero boundary rows.
// ---------------------------------------------------------------------------
__global__ __launch_bounds__(256, 1) void chain_kernel(float* __restrict__ th,
                                                       const unsigned short* __restrict__ whhbf,
                                                       const unsigned short* __restrict__ wihbf,
                                                       const float* __restrict__ biasz,
                                                       const int* __restrict__ idxb,
                                                       const int* __restrict__ flags) {
    const int b = blockIdx.x;
    const int t = threadIdx.x;
    const int l = t & 63, lr = l & 15, lg = l >> 4;
    const int w = t >> 6, dir = w >> 1, ww = w & 1;

    __shared__ __align__(16) unsigned short thl[128 * 256];         // 64 KB swizzled bf16
    __shared__ __align__(16) unsigned short xgs3[2 * 2 * 16 * 256]; // 32 KB [dir][ww][m][lr][16]
    __shared__ __align__(16) unsigned short hsnap[2][18][128];      // 9 KB h history + 0-rows
    __shared__ int idxl[2048];                                      // 8 KB
    __shared__ int flg[128];

    // ---- load th slice -> bf16 LDS (swizzled); row r = t>>1, 128 floats each
    {
        int r = t >> 1, c0 = (t & 1) * 128;
        const float* src = th + (size_t)(b * 128 + r) * 256 + c0;
        char* rowb = (char*)thl + r * 512;
        int swz = (r & 7) << 4;
#pragma unroll
        for (int i = 0; i < 16; ++i) {
            float4 v0 = *(const float4*)(src + i * 8);
            float4 v1 = *(const float4*)(src + i * 8 + 4);
            *(bf16x8*)(rowb + (((c0 + i * 8) * 2) ^ swz)) = pack8(v0, v1);
        }
    }
    if (t < 128) flg[t] = flags[b * 128 + t];
    {   // permanent zero boundary rows (initial LSTM state)
        int d2 = t >> 7, j = t & 127;
        hsnap[d2][0][j] = 0;
        hsnap[d2][17][j] = 0;
    }
#pragma unroll
    for (int c = 0; c < 8; ++c) idxl[t + c * 256] = idxb[(size_t)b * 2048 + c * 256 + t];

    // ---- resident Whh bf16 B-fragments: 64 frags = 256 regs (512 budget)
    bf16x8 wf[4][4][4];   // [G][q][kc]
    {
        const unsigned short* whh = whhbf + (size_t)dir * 65536;
#pragma unroll
        for (int G = 0; G < 4; ++G)
#pragma unroll
            for (int q = 0; q < 4; ++q) {
                int gate = G * 128 + ww * 64 + q * 16 + lr;
#pragma unroll
                for (int kc = 0; kc < 4; ++kc)
                    wf[G][q][kc] = *(const bf16x8*)(whh + (size_t)gate * 128 + kc * 32 + lg * 8);
            }
    }
    const unsigned short* wih = wihbf + (size_t)dir * 131072;
    float bzr[16];
#pragma unroll
    for (int G = 0; G < 4; ++G)
#pragma unroll
        for (int q = 0; q < 4; ++q)
            bzr[G * 4 + q] = biasz[dir * 512 + G * 128 + ww * 64 + q * 16 + lr];
    __syncthreads();

    const int xgbase = (dir * 2 + ww) * 16 * 256;   // u16 elements; 256 per member

    for (int ag = 0; ag < 128; ++ag) {
        if (!flg[ag]) continue;
        const int gi_lr = idxl[ag * 16 + lr];

        // xg: A rows = 16 members, B = Wih streamed from L2; 128 MFMA/wave,
        // bias-seeded accumulators. Covers this wave's 256 gates.
        {
            f32x4 xa[4][4];
#pragma unroll
            for (int G = 0; G < 4; ++G)
#pragma unroll
                for (int q = 0; q < 4; ++q) {
                    float bb = bzr[G * 4 + q];
                    xa[G][q] = (f32x4){bb, bb, bb, bb};
                }
            const char* arow = (const char*)thl + gi_lr * 512;
            const int aswz = (gi_lr & 7) << 4;
#pragma unroll
            for (int kc = 0; kc < 8; ++kc) {
                bf16x8 af = *(const bf16x8*)(arow + ((kc * 64 + lg * 16) ^ aswz));
#pragma unroll
                for (int G = 0; G < 4; ++G)
#pragma unroll
                    for (int q = 0; q < 4; ++q) {
                        const unsigned short* wb =
                            wih + (size_t)(G * 128 + ww * 64 + q * 16 + lr) * 256 +
                            kc * 32 + lg * 8;
                        xa[G][q] = __builtin_amdgcn_mfma_f32_16x16x32_bf16(
                            af, *(const bf16x8*)wb, xa[G][q], 0, 0, 0);
                    }
            }
            // store: [dirww][m][lr][16] ; idx 0..7 = G0q0..3,G1q0..3 ; 8..15 = G2,G3
#pragma unroll
            for (int r = 0; r < 4; ++r) {
                bf16x8 p0, p1;
#pragma unroll
                for (int q = 0; q < 4; ++q) {
                    p0[q]     = (short)f2bf(xa[0][q][r]);
                    p0[4 + q] = (short)f2bf(xa[1][q][r]);
                    p1[q]     = (short)f2bf(xa[2][q][r]);
                    p1[4 + q] = (short)f2bf(xa[3][q][r]);
                }
                int m = lg * 4 + r;
                unsigned short* dst = &xgs3[xgbase + m * 256 + lr * 16];
                *(bf16x8*)dst = p0;
                *(bf16x8*)(dst + 8) = p1;
            }
        }
        __syncthreads();   // xgs3 ready

        // preload xg for first step
        const int m0 = dir ? 15 : 0;
        bf16x8 xq0 = *(const bf16x8*)&xgs3[xgbase + m0 * 256 + lr * 16];
        bf16x8 xq1 = *(const bf16x8*)&xgs3[xgbase + m0 * 256 + lr * 16 + 8];

        // 16-step recurrence: 4x ds_read_b128 (h) + 64 MFMA + acts +
        // 1x ds_write_b16/lane + 2x b128 prefetch; ONE 4-wave barrier/step
        float cst[4] = {0.f, 0.f, 0.f, 0.f};
        for (int s = 0; s < 16; ++s) {
            const int m = dir ? (15 - s) : s;
            const int rprev = dir ? (m + 2) : m;
            f32x4 acc[4][4];
#pragma unroll
            for (int G = 0; G < 4; ++G)
#pragma unroll
                for (int q = 0; q < 4; ++q) acc[G][q] = (f32x4){0.f, 0.f, 0.f, 0.f};
#pragma unroll
            for (int kc = 0; kc < 4; ++kc) {
                bf16x8 ha = *(const bf16x8*)(&hsnap[dir][rprev][kc * 32 + lg * 8]);
#pragma unroll
                for (int G = 0; G < 4; ++G)
#pragma unroll
                    for (int q = 0; q < 4; ++q)
                        acc[G][q] = __builtin_amdgcn_mfma_f32_16x16x32_bf16(
                            ha, wf[G][q][kc], acc[G][q], 0, 0, 0);
            }
            bf16x8 x0 = xq0, x1 = xq1;
            float hq[4];
#pragma unroll
            for (int q = 0; q < 4; ++q) {
                float zi = acc[0][q][0] + bf2f((unsigned short)x0[q]);
                float zf = acc[1][q][0] + bf2f((unsigned short)x0[4 + q]);
                float zg = acc[2][q][0] + bf2f((unsigned short)x1[q]);
                float zo = acc[3][q][0] + bf2f((unsigned short)x1[4 + q]);
                float ig = fsig(zi), fg = fsig(zf), gv = ftanh(zg), og = fsig(zo);
                cst[q] = fg * cst[q] + ig * gv;
                hq[q] = og * ftanh(cst[q]);
            }
            // lane (lg,lr) writes unit ww*64 + lg*16 + lr  (h = hq[lg])
            float hsel = (lg == 0) ? hq[0] : (lg == 1) ? hq[1] : (lg == 2) ? hq[2] : hq[3];
            hsnap[dir][m + 1][ww * 64 + lg * 16 + lr] = f2bf(hsel);
            if (s < 15) {
                int mn = dir ? (14 - s) : (s + 1);
                xq0 = *(const bf16x8*)&xgs3[xgbase + mn * 256 + lr * 16];
                xq1 = *(const bf16x8*)&xgs3[xgbase + mn * 256 + lr * 16 + 8];
            }
            __syncthreads();
        }

        // bulk scatter hsnap -> thl (swizzled): 512 b128 items / 256 threads
        {
#pragma unroll
            for (int i = 0; i < 2; ++i) {
                int item = t + i * 256;
                int d2 = item >> 8, m = (item >> 4) & 15, c8 = (item & 15) * 8;
                bf16x8 v = *(const bf16x8*)&hsnap[d2][m + 1][c8];
                int row = idxl[ag * 16 + m];
                *(bf16x8*)((char*)thl + row * 512 +
                           (((d2 * 128 + c8) * 2) ^ ((row & 7) << 4))) = v;
            }
        }
        __syncthreads();
    }

    // ---- write back the whole slice (un-swizzle, bf16 -> fp32)
    {
        int r = t >> 1, c0 = (t & 1) * 128;
        const char* rowb = (const char*)thl + r * 512;
        int swz = (r & 7) << 4;
        float* dst = th + (size_t)(b * 128 + r) * 256 + c0;
#pragma unroll
        for (int i = 0; i < 16; ++i) {
            bf16x8 sv = *(const bf16x8*)(rowb + (((c0 + i * 8) * 2) ^ swz));
            float4 v0, v1;
            v0.x = bf2f((unsigned short)sv[0]); v0.y = bf2f((unsigned short)sv[1]);
            v0.z = bf2f((unsigned short)sv[2]); v0.w = bf2f((unsigned short)sv[3]);
            v1.x = bf2f((unsigned short)sv[4]); v1.y = bf2f((unsigned short)sv[5]);
            v1.z = bf2f((unsigned short)sv[6]); v1.w = bf2f((unsigned short)sv[7]);
            *(float4*)(dst + i * 8) = v0;
            *(float4*)(dst + i * 8 + 4) = v1;
        }
    }
}

// ---------------------------------------------------------------------------
extern "C" void kernel_launch(void* const* d_in, const int* in_sizes, int n_in,
                              void* d_out, int out_size, void* d_ws, size_t ws_size,
                              hipStream_t stream) {
    const float* obs  = (const float*)d_in[0];
    const float* W1   = (const float*)d_in[1];
    const float* b1   = (const float*)d_in[2];
    const float* gg1  = (const float*)d_in[3];
    const float* be1  = (const float*)d_in[4];
    const float* W2   = (const float*)d_in[5];
    const float* b2   = (const float*)d_in[6];
    const float* gg2  = (const float*)d_in[7];
    const float* be2  = (const float*)d_in[8];
    const float* Wa1  = (const float*)d_in[9];
    const float* ba1  = (const float*)d_in[10];
    const float* Wa2  = (const float*)d_in[11];
    const float* ba2  = (const float*)d_in[12];
    const float* Wa3  = (const float*)d_in[13];
    const float* ba3  = (const float*)d_in[14];
    const float* Wf_ih = (const float*)d_in[15];
    const float* Wf_hh = (const float*)d_in[16];
    const float* bf_ih = (const float*)d_in[17];
    const float* bf_hh = (const float*)d_in[18];
    const float* Wb_ih = (const float*)d_in[19];
    const float* Wb_hh = (const float*)d_in[20];
    const float* bb_ih = (const float*)d_in[21];
    const float* bb_hh = (const float*)d_in[22];
    const float* W3   = (const float*)d_in[23];
    const float* b3   = (const float*)d_in[24];
    const float* gg3  = (const float*)d_in[25];
    const float* be3  = (const float*)d_in[26];
    const float* W4   = (const float*)d_in[27];
    const float* b4   = (const float*)d_in[28];
    const float* gg4  = (const float*)d_in[29];
    const float* be4  = (const float*)d_in[30];

    float* out     = (float*)d_out;
    float* out_acts = out;                   // 128*128*64
    float* out_C    = out + 1048576;         // 128*128*128
    float* out_ip   = out + 3145728;         // 16384
    float* out_ii   = out + 3162112;         // 16384
    float* out_nt   = out + 3178496;         // 128*128*256 (evolving thoughts)
    float* out_ot   = out + 7372800;         // 128*128*256 (old thoughts)

    float* ws    = (float*)d_ws;
    float* h1    = ws;                               // 4194304
    float* abuf  = ws + 4194304;                     // 2097152 (a1, later dot)
    float* a2buf = ws + 6291456;                     // 2097152 (a2, later act-pre)
    unsigned short* wihbf = (unsigned short*)(ws + 8388608);  // 262144 shorts
    float* biasz = ws + 8519680;                     // 1024
    unsigned short* whhbf = (unsigned short*)(ws + 8520704);  // 131072 shorts
    float* sqb   = ws + 8586240;                     // 16384
    int* idxb    = (int*)(ws + 8602624);             // 262144
    int* flagsb  = (int*)(ws + 8864768);             // 16384

    prep_kernel<<<512, 256, 0, stream>>>(Wf_ih, Wb_ih, Wf_hh, Wb_hh,
                                         bf_ih, bf_hh, bb_ih, bb_hh,
                                         wihbf, whhbf, biasz);

    // actor_1
    gemm64<<<dim3(4, 256), 256, 0, stream>>>(obs, W1, b1, h1, 16384, 256, 512, 0);
    ln256_kernel<<<4096, 256, 0, stream>>>(h1, h1, nullptr, gg1, be1, 1);
    gemm64<<<dim3(4, 256), 256, 0, stream>>>(h1, W2, b2, out_nt, 16384, 256, 256, 0);
    ln256_kernel<<<4096, 256, 0, stream>>>(out_nt, out_nt, out_ot, gg2, be2, 0);

    // attention unit
    gemm64<<<dim3(2, 256), 256, 0, stream>>>(out_nt, Wa1, ba1, abuf, 16384, 128, 256, 1);
    gemm64<<<dim3(2, 256), 256, 0, stream>>>(abuf, Wa2, ba2, a2buf, 16384, 128, 128, 1);
    attn_head_kernel<<<4096, 256, 0, stream>>>(a2buf, Wa3, ba3, out_ip, out_ii, flagsb);

    // pairwise distances + top-16
    dot_kernel<<<256, 256, 0, stream>>>(out_nt, abuf);
    sq_kernel<<<64, 256, 0, stream>>>(abuf, sqb);
    topk_kernel<<<4096, 256, 0, stream>>>(abuf, sqb, flagsb, out_C, idxb);

    // sequential communication chain (mutates out_nt), all-LDS agent loop
    chain_kernel<<<128, 256, 0, stream>>>(out_nt, whhbf, wihbf, biasz, idxb, flagsb);

    // actor_2
    gemm64<<<dim3(4, 256), 256, 0, stream>>>(out_nt, W3, b3, h1, 16384, 256, 256, 2);
    ln256_kernel<<<4096, 256, 0, stream>>>(h1, h1, nullptr, gg3, be3, 0);
    gemm64<<<dim3(1, 256), 256, 0, stream>>>(h1, W4, b4, a2buf, 16384, 64, 256, 0);
    ln64_tanh_kernel<<<4096, 256, 0, stream>>>(a2buf, out_acts, gg4, be4);
}

// Round 12
// 3763.594 us; speedup vs baseline: 1.2176x; 1.2176x over previous
//
#include <hip/hip_runtime.h>
#include <math.h>

typedef __attribute__((ext_vector_type(8))) short bf16x8;
typedef __attribute__((ext_vector_type(4))) float f32x4;

__device__ __forceinline__ unsigned short f2bf(float x) {
    unsigned int u = __float_as_uint(x);
    u += 0x7fffu + ((u >> 16) & 1u);
    return (unsigned short)(u >> 16);
}
__device__ __forceinline__ float bf2f(unsigned short b) {
    return __uint_as_float(((unsigned int)b) << 16);
}
// fast activations: v_exp_f32 + v_rcp_f32 (rel err ~1e-7, far below bf16 noise)
__device__ __forceinline__ float fsig(float z) {
    float e = __expf(-z);
    return __builtin_amdgcn_rcpf(1.f + e);
}
// tanh(x) = 2*sigmoid(2x) - 1
__device__ __forceinline__ float ftanh(float x) {
    float e = __expf(-2.f * x);
    float s = __builtin_amdgcn_rcpf(1.f + e);
    return fmaf(2.f, s, -1.f);
}
__device__ __forceinline__ bf16x8 pack8(float4 a, float4 b) {
    bf16x8 r;
    r[0] = (short)f2bf(a.x); r[1] = (short)f2bf(a.y);
    r[2] = (short)f2bf(a.z); r[3] = (short)f2bf(a.w);
    r[4] = (short)f2bf(b.x); r[5] = (short)f2bf(b.y);
    r[6] = (short)f2bf(b.z); r[7] = (short)f2bf(b.w);
    return r;
}
// LDS-only barrier: the recurrence loop has no VMEM in flight, so skip the
// vmcnt/expcnt drain that __syncthreads() would impose (rule #18 fence).
__device__ __forceinline__ void lds_barrier() {
    asm volatile("s_waitcnt lgkmcnt(0)" ::: "memory");
    __builtin_amdgcn_sched_barrier(0);
    __builtin_amdgcn_s_barrier();
}

// ---------------------------------------------------------------------------
// prep: convert Wih and Whh to bf16, bias sums
// ---------------------------------------------------------------------------
__global__ void prep_kernel(const float* __restrict__ Wf_ih, const float* __restrict__ Wb_ih,
                            const float* __restrict__ Wf_hh, const float* __restrict__ Wb_hh,
                            const float* __restrict__ bf_ih, const float* __restrict__ bf_hh,
                            const float* __restrict__ bb_ih, const float* __restrict__ bb_hh,
                            unsigned short* __restrict__ wihbf,
                            unsigned short* __restrict__ whhbf,
                            float* __restrict__ biasz) {
    int i = blockIdx.x * 256 + threadIdx.x;   // grid 512*256 = 131072
    if (i < 131072) {
        wihbf[i]          = f2bf(Wf_ih[i]);
        wihbf[131072 + i] = f2bf(Wb_ih[i]);
    }
    if (i < 65536) {
        whhbf[i]         = f2bf(Wf_hh[i]);
        whhbf[65536 + i] = f2bf(Wb_hh[i]);
    }
    if (i < 512) {
        biasz[i]       = bf_ih[i] + bf_hh[i];
        biasz[512 + i] = bb_ih[i] + bb_hh[i];
    }
}

// ---------------------------------------------------------------------------
// generic fp32 GEMM  C[M,N] = A[M,K] @ B[K,N] + bias ; flags: 1=relu_out 2=relu_A
// ---------------------------------------------------------------------------
__global__ __launch_bounds__(256) void gemm64(const float* __restrict__ A,
                                              const float* __restrict__ Bm,
                                              const float* __restrict__ bias,
                                              float* __restrict__ C,
                                              int M, int N, int K, int flags) {
    __shared__ float As[16][68];
    __shared__ float Bs[16][68];
    const int t = threadIdx.x;
    const int row0 = blockIdx.y * 64, col0 = blockIdx.x * 64;
    const int tm = t >> 4, tn = t & 15;
    float acc[4][4] = {};
    for (int k0 = 0; k0 < K; k0 += 16) {
        {
            int r = t >> 2, kq = (t & 3) * 4;
            float4 v = *(const float4*)(A + (size_t)(row0 + r) * K + k0 + kq);
            if (flags & 2) {
                v.x = fmaxf(v.x, 0.f); v.y = fmaxf(v.y, 0.f);
                v.z = fmaxf(v.z, 0.f); v.w = fmaxf(v.w, 0.f);
            }
            As[kq + 0][r] = v.x; As[kq + 1][r] = v.y;
            As[kq + 2][r] = v.z; As[kq + 3][r] = v.w;
        }
        {
            int kk = t >> 4, nq = (t & 15) * 4;
            float4 v = *(const float4*)(Bm + (size_t)(k0 + kk) * N + col0 + nq);
            *(float4*)&Bs[kk][nq] = v;
        }
        __syncthreads();
#pragma unroll
        for (int kk = 0; kk < 16; ++kk) {
            float a[4], b[4];
#pragma unroll
            for (int i = 0; i < 4; ++i) a[i] = As[kk][tm * 4 + i];
#pragma unroll
            for (int j = 0; j < 4; ++j) b[j] = Bs[kk][tn * 4 + j];
#pragma unroll
            for (int i = 0; i < 4; ++i)
#pragma unroll
                for (int j = 0; j < 4; ++j) acc[i][j] = fmaf(a[i], b[j], acc[i][j]);
        }
        __syncthreads();
    }
#pragma unroll
    for (int i = 0; i < 4; ++i) {
#pragma unroll
        for (int j = 0; j < 4; ++j) {
            int col = col0 + tn * 4 + j;
            float v = acc[i][j] + (bias ? bias[col] : 0.f);
            if (flags & 1) v = fmaxf(v, 0.f);
            C[(size_t)(row0 + tm * 4 + i) * N + col] = v;
        }
    }
}

// ---------------------------------------------------------------------------
// LayerNorm over 256, one wave per row. Optional relu, optional dup output.
// ---------------------------------------------------------------------------
__global__ __launch_bounds__(256) void ln256_kernel(const float* __restrict__ X,
                                                    float* __restrict__ Y,
                                                    float* __restrict__ Y2,
                                                    const float* __restrict__ gam,
                                                    const float* __restrict__ bet,
                                                    int relu) {
#pragma clang fp contract(off)
    int row = blockIdx.x * 4 + (threadIdx.x >> 6);
    int l = threadIdx.x & 63;
    float4 x = *(const float4*)(X + (size_t)row * 256 + l * 4);
    float s = x.x + x.y + x.z + x.w;
#pragma unroll
    for (int d = 1; d < 64; d <<= 1) s += __shfl_xor(s, d);
    float mu = s * (1.f / 256.f);
    float d0 = x.x - mu, d1 = x.y - mu, d2 = x.z - mu, d3 = x.w - mu;
    float ss = d0 * d0 + d1 * d1 + d2 * d2 + d3 * d3;
#pragma unroll
    for (int d = 1; d < 64; d <<= 1) ss += __shfl_xor(ss, d);
    float var = ss * (1.f / 256.f);
    float sd = sqrtf(var + 1e-5f);
    float4 y;
    y.x = (d0 / sd) * gam[l * 4 + 0] + bet[l * 4 + 0];
    y.y = (d1 / sd) * gam[l * 4 + 1] + bet[l * 4 + 1];
    y.z = (d2 / sd) * gam[l * 4 + 2] + bet[l * 4 + 2];
    y.w = (d3 / sd) * gam[l * 4 + 3] + bet[l * 4 + 3];
    if (relu) {
        y.x = fmaxf(y.x, 0.f); y.y = fmaxf(y.y, 0.f);
        y.z = fmaxf(y.z, 0.f); y.w = fmaxf(y.w, 0.f);
    }
    *(float4*)(Y + (size_t)row * 256 + l * 4) = y;
    if (Y2) *(float4*)(Y2 + (size_t)row * 256 + l * 4) = y;
}

// LayerNorm over 64 + tanh, one wave per row
__global__ __launch_bounds__(256) void ln64_tanh_kernel(const float* __restrict__ X,
                                                        float* __restrict__ Y,
                                                        const float* __restrict__ gam,
                                                        const float* __restrict__ bet) {
#pragma clang fp contract(off)
    int row = blockIdx.x * 4 + (threadIdx.x >> 6);
    int l = threadIdx.x & 63;
    float x = X[(size_t)row * 64 + l];
    float s = x;
#pragma unroll
    for (int d = 1; d < 64; d <<= 1) s += __shfl_xor(s, d);
    float mu = s * (1.f / 64.f);
    float dx = x - mu;
    float ss = dx * dx;
#pragma unroll
    for (int d = 1; d < 64; d <<= 1) ss += __shfl_xor(ss, d);
    float var = ss * (1.f / 64.f);
    float sd = sqrtf(var + 1e-5f);
    float y = tanhf((dx / sd) * gam[l] + bet[l]);
    Y[(size_t)row * 64 + l] = y;
}

// ---------------------------------------------------------------------------
// attention head: p = sigmoid(a2 @ Wa3 + ba3), flags = p > 0.4
// ---------------------------------------------------------------------------
__global__ __launch_bounds__(256) void attn_head_kernel(const float* __restrict__ a2,
                                                        const float* __restrict__ Wa3,
                                                        const float* __restrict__ ba3,
                                                        float* __restrict__ outP,
                                                        float* __restrict__ outInit,
                                                        int* __restrict__ flags) {
#pragma clang fp contract(off)
    int row = blockIdx.x * 4 + (threadIdx.x >> 6);
    int l = threadIdx.x & 63;
    float s = a2[(size_t)row * 128 + l] * Wa3[l] + a2[(size_t)row * 128 + 64 + l] * Wa3[64 + l];
#pragma unroll
    for (int d = 1; d < 64; d <<= 1) s += __shfl_xor(s, d);
    s += ba3[0];
    float p = 1.f / (1.f + expf(-s));
    if (l == 0) {
        outP[row] = p;
        int f = (p > 0.4f) ? 1 : 0;
        outInit[row] = f ? 1.f : 0.f;
        flags[row] = f;
    }
}

// ---------------------------------------------------------------------------
// batched dot: dot[b] = th_b @ th_b^T   (128x128, K=256); 2 blocks per batch
// ---------------------------------------------------------------------------
__global__ __launch_bounds__(256) void dot_kernel(const float* __restrict__ th,
                                                  float* __restrict__ dotm) {
    __shared__ float As[16][68];
    __shared__ float Bs[16][132];
    const int b = blockIdx.x >> 1, half = blockIdx.x & 1;
    const int t = threadIdx.x;
    const int tm = t >> 4, tn = t & 15;
    float acc[4][8] = {};
    const float* base = th + (size_t)b * 128 * 256;
    for (int k0 = 0; k0 < 256; k0 += 16) {
        {
            int r = t >> 2, kq = (t & 3) * 4;
            float4 v = *(const float4*)(base + (size_t)(half * 64 + r) * 256 + k0 + kq);
            As[kq + 0][r] = v.x; As[kq + 1][r] = v.y;
            As[kq + 2][r] = v.z; As[kq + 3][r] = v.w;
        }
        {
            int n = t >> 1, kq = (t & 1) * 8;
            const float* src = base + (size_t)n * 256 + k0 + kq;
            float4 v0 = *(const float4*)src;
            float4 v1 = *(const float4*)(src + 4);
            Bs[kq + 0][n] = v0.x; Bs[kq + 1][n] = v0.y;
            Bs[kq + 2][n] = v0.z; Bs[kq + 3][n] = v0.w;
            Bs[kq + 4][n] = v1.x; Bs[kq + 5][n] = v1.y;
            Bs[kq + 6][n] = v1.z; Bs[kq + 7][n] = v1.w;
        }
        __syncthreads();
#pragma unroll
        for (int kk = 0; kk < 16; ++kk) {
            float a[4], bb[8];
#pragma unroll
            for (int i = 0; i < 4; ++i) a[i] = As[kk][tm * 4 + i];
#pragma unroll
            for (int j = 0; j < 8; ++j) bb[j] = Bs[kk][tn * 8 + j];
#pragma unroll
            for (int i = 0; i < 4; ++i)
#pragma unroll
                for (int j = 0; j < 8; ++j) acc[i][j] = fmaf(a[i], bb[j], acc[i][j]);
        }
        __syncthreads();
    }
#pragma unroll
    for (int i = 0; i < 4; ++i)
#pragma unroll
        for (int j = 0; j < 8; ++j)
            dotm[(size_t)b * 16384 + (size_t)(half * 64 + tm * 4 + i) * 128 + tn * 8 + j] = acc[i][j];
}

__global__ void sq_kernel(const float* __restrict__ dotm, float* __restrict__ sq) {
    int i = blockIdx.x * 256 + threadIdx.x;   // 64 blocks
    int b = i >> 7, n = i & 127;
    sq[i] = dotm[(size_t)b * 16384 + (size_t)n * 129];
}

// ---------------------------------------------------------------------------
// top-16 smallest distances per row (ties -> lower index), write C + idx
// ---------------------------------------------------------------------------
__global__ __launch_bounds__(256) void topk_kernel(const float* __restrict__ dotm,
                                                   const float* __restrict__ sq,
                                                   const int* __restrict__ flags,
                                                   float* __restrict__ outC,
                                                   int* __restrict__ idxb) {
#pragma clang fp contract(off)
    int row = blockIdx.x * 4 + (threadIdx.x >> 6);
    int l = threadIdx.x & 63;
    int b = row >> 7;
    const float* drow = dotm + (size_t)row * 128;
    float sqi = sq[row];
    float t0 = 2.f * drow[l];
    float v0 = sq[b * 128 + l] - t0; v0 = v0 + sqi;
    float t1 = 2.f * drow[64 + l];
    float v1 = sq[b * 128 + 64 + l] - t1; v1 = v1 + sqi;

    unsigned long long mlo = 0ull, mhi = 0ull;
#pragma unroll 1
    for (int n = 0; n < 16; ++n) {
        float bv = v0; int bi = l;
        if (v1 < bv) { bv = v1; bi = 64 + l; }
#pragma unroll
        for (int d = 1; d < 64; d <<= 1) {
            float ov = __shfl_xor(bv, d);
            int oi = __shfl_xor(bi, d);
            if (ov < bv || (ov == bv && oi < bi)) { bv = ov; bi = oi; }
        }
        if (bi < 64) mlo |= (1ull << bi); else mhi |= (1ull << (bi - 64));
        if (l == bi) v0 = __builtin_inff();
        if (64 + l == bi) v1 = __builtin_inff();
    }
    float fl = (flags[row] != 0) ? 1.f : 0.f;
    outC[(size_t)row * 128 + l]      = fl * (((mlo >> l) & 1ull) ? 1.f : 0.f);
    outC[(size_t)row * 128 + 64 + l] = fl * (((mhi >> l) & 1ull) ? 1.f : 0.f);
    if (l < 16) {
        int cnt = 0, found = -1;
        for (int jj = 0; jj < 128; ++jj) {
            bool bit = (jj < 64) ? ((mlo >> jj) & 1ull) : ((mhi >> (jj - 64)) & 1ull);
            if (bit) { if (cnt == l) { found = jj; break; } ++cnt; }
        }
        idxb[(size_t)row * 16 + l] = found;
    }
}

// ---------------------------------------------------------------------------
// THE CHAIN (R7, best measured: 3331 us): one 512-thread block per batch,
// 8 waves (4 fwd, 4 bwd), 2/SIMD. Lane lr of wave wd owns adjacent units
// {wd*32+2lr, +1}. h history in hsnap[2][18][128] (rows 0/17 permanent
// zero). Per-step: 4x ds_read_b128 (h) + 16 MFMA + acts + 1x ds_write_b32
// + 1x b128 xg prefetch + ONE lgkm-only barrier (loop is LDS-only; skip
// the vmcnt drain __syncthreads would add).
// ---------------------------------------------------------------------------
__global__ __launch_bounds__(512, 2) void chain_kernel(float* __restrict__ th,
                                                       const unsigned short* __restrict__ whhbf,
                                                       const unsigned short* __restrict__ wihbf,
                                                       const float* __restrict__ biasz,
                                                       const int* __restrict__ idxb,
                                                       const int* __restrict__ flags) {
    const int b = blockIdx.x;
    const int t = threadIdx.x;
    const int l = t & 63, lr = l & 15, lg = l >> 4;
    const int w = t >> 6, dir = w >> 2, wd = w & 3;

    __shared__ __align__(16) unsigned short thl[128 * 256];        // 64 KB swizzled bf16
    __shared__ __align__(16) unsigned short xgs2[2 * 4 * 16 * 16 * 8]; // 32 KB [dir][wd][m][lr][8]
    __shared__ __align__(16) unsigned short hsnap[2][18][128];     // 9 KB h history + 0-rows
    __shared__ int idxl[2048];                                     // 8 KB
    __shared__ int flg[128];

    // ---- load th slice -> bf16 LDS (swizzled); row r = t>>2, 64 floats each
    {
        int r = t >> 2, c0 = (t & 3) * 64;
        const float* src = th + (size_t)(b * 128 + r) * 256 + c0;
        char* rowb = (char*)thl + r * 512;
        int swz = (r & 7) << 4;
#pragma unroll
        for (int i = 0; i < 8; ++i) {
            float4 v0 = *(const float4*)(src + i * 8);
            float4 v1 = *(const float4*)(src + i * 8 + 4);
            *(bf16x8*)(rowb + (((c0 + i * 8) * 2) ^ swz)) = pack8(v0, v1);
        }
    }
    if (t < 128) flg[t] = flags[b * 128 + t];
    if (t < 256) {   // permanent zero boundary rows (initial LSTM state)
        int d2 = t >> 7, j = t & 127;
        hsnap[d2][0][j] = 0;
        hsnap[d2][17][j] = 0;
    }
#pragma unroll
    for (int c = 0; c < 4; ++c) idxl[t + c * 512] = idxb[(size_t)b * 2048 + c * 512 + t];

    // ---- resident Whh bf16 B-fragments: 32 frags = 128 regs
    bf16x8 wf[4][2][4];
    {
        const unsigned short* whh = whhbf + (size_t)dir * 65536;
#pragma unroll
        for (int G = 0; G < 4; ++G)
#pragma unroll
            for (int hf = 0; hf < 2; ++hf) {
                int gate = G * 128 + wd * 32 + 2 * lr + hf;
#pragma unroll
                for (int kc = 0; kc < 4; ++kc)
                    wf[G][hf][kc] = *(const bf16x8*)(whh + (size_t)gate * 128 + kc * 32 + lg * 8);
            }
    }
    const unsigned short* wih = wihbf + (size_t)dir * 131072;
    float bzr[8];
#pragma unroll
    for (int tt = 0; tt < 8; ++tt)
        bzr[tt] = biasz[dir * 512 + (tt >> 1) * 128 + wd * 32 + 2 * lr + (tt & 1)];
    __syncthreads();

    const int xgbase = ((dir * 4 + wd) * 16) * 16 * 8;   // this wave's xg slab

    for (int ag = 0; ag < 128; ++ag) {
        if (!flg[ag]) continue;
        const int gi_lr = idxl[ag * 16 + lr];

        // xg: A rows = 16 members (thl rows gi), B = Wih streamed from L2,
        // bias-seeded accumulators.
        {
            f32x4 xa[8];
#pragma unroll
            for (int tt = 0; tt < 8; ++tt)
                xa[tt] = (f32x4){bzr[tt], bzr[tt], bzr[tt], bzr[tt]};
            const char* arow = (const char*)thl + gi_lr * 512;
            const int aswz = (gi_lr & 7) << 4;
#pragma unroll
            for (int kc = 0; kc < 8; ++kc) {
                bf16x8 af = *(const bf16x8*)(arow + ((kc * 64 + lg * 16) ^ aswz));
#pragma unroll
                for (int tt = 0; tt < 8; ++tt) {
                    const unsigned short* wb =
                        wih + (size_t)((tt >> 1) * 128 + wd * 32 + 2 * lr + (tt & 1)) * 256 +
                        kc * 32 + lg * 8;
                    xa[tt] = __builtin_amdgcn_mfma_f32_16x16x32_bf16(
                        af, *(const bf16x8*)wb, xa[tt], 0, 0, 0);
                }
            }
            // store transposed: [dir][wd][m][lr][8 gates] -> one b128 per (m,lr)
#pragma unroll
            for (int r = 0; r < 4; ++r) {
                bf16x8 pk;
#pragma unroll
                for (int tt = 0; tt < 8; ++tt) pk[tt] = (short)f2bf(xa[tt][r]);
                int m = lg * 4 + r;
                *(bf16x8*)&xgs2[xgbase + (m * 16 + lr) * 8] = pk;
            }
        }
        __syncthreads();   // xgs2 ready (global loads in flight: full barrier)

        // preload xg for first step
        bf16x8 xpn = *(const bf16x8*)&xgs2[xgbase + ((dir ? 15 : 0) * 16 + lr) * 8];

        // 16-step recurrence: 4x ds_read_b128 (h) + 16 MFMA + acts +
        // 1x ds_write_b32 + 1x b128 prefetch per step; lgkm-only barrier
        float cst0 = 0.f, cst1 = 0.f;
        for (int s = 0; s < 16; ++s) {
            const int m = dir ? (15 - s) : s;
            const int rprev = dir ? (m + 2) : m;
            bf16x8 xp = xpn;
            f32x4 acc[4][2];
#pragma unroll
            for (int G = 0; G < 4; ++G) {
                acc[G][0] = (f32x4){0.f, 0.f, 0.f, 0.f};
                acc[G][1] = (f32x4){0.f, 0.f, 0.f, 0.f};
            }
#pragma unroll
            for (int kc = 0; kc < 4; ++kc) {
                bf16x8 ha = *(const bf16x8*)(&hsnap[dir][rprev][kc * 32 + lg * 8]);
#pragma unroll
                for (int G = 0; G < 4; ++G) {
                    acc[G][0] = __builtin_amdgcn_mfma_f32_16x16x32_bf16(
                        ha, wf[G][0][kc], acc[G][0], 0, 0, 0);
                    acc[G][1] = __builtin_amdgcn_mfma_f32_16x16x32_bf16(
                        ha, wf[G][1][kc], acc[G][1], 0, 0, 0);
                }
            }
            float zi0 = acc[0][0][0] + bf2f((unsigned short)xp[0]);
            float zi1 = acc[0][1][0] + bf2f((unsigned short)xp[1]);
            float zf0 = acc[1][0][0] + bf2f((unsigned short)xp[2]);
            float zf1 = acc[1][1][0] + bf2f((unsigned short)xp[3]);
            float zg0 = acc[2][0][0] + bf2f((unsigned short)xp[4]);
            float zg1 = acc[2][1][0] + bf2f((unsigned short)xp[5]);
            float zo0 = acc[3][0][0] + bf2f((unsigned short)xp[6]);
            float zo1 = acc[3][1][0] + bf2f((unsigned short)xp[7]);
            float i0 = fsig(zi0), f0 = fsig(zf0), g0 = ftanh(zg0), o0 = fsig(zo0);
            cst0 = f0 * cst0 + i0 * g0;
            float h0 = o0 * ftanh(cst0);
            float i1 = fsig(zi1), f1 = fsig(zf1), g1 = ftanh(zg1), o1 = fsig(zo1);
            cst1 = f1 * cst1 + i1 * g1;
            float h1 = o1 * ftanh(cst1);
            if (lg == 0) {
                unsigned int hw = (unsigned int)f2bf(h0) | ((unsigned int)f2bf(h1) << 16);
                *(unsigned int*)&hsnap[dir][m + 1][wd * 32 + 2 * lr] = hw;
            }
            // prefetch next step's xg (hides ds latency under barrier wait)
            if (s < 15) {
                int mn = dir ? (14 - s) : (s + 1);
                xpn = *(const bf16x8*)&xgs2[xgbase + (mn * 16 + lr) * 8];
            }
            lds_barrier();
        }

        // bulk scatter hsnap -> thl (swizzled), 512 threads cover 2*16*128
        {
            int d2 = t >> 8, m = (t >> 4) & 15, c8 = (t & 15) * 8;
            bf16x8 v = *(const bf16x8*)&hsnap[d2][m + 1][c8];
            int row = idxl[ag * 16 + m];
            *(bf16x8*)((char*)thl + row * 512 + (((d2 * 128 + c8) * 2) ^ ((row & 7) << 4))) = v;
        }
        lds_barrier();
    }

    // ---- write back the whole slice (un-swizzle, bf16 -> fp32)
    {
        int r = t >> 2, c0 = (t & 3) * 64;
        const char* rowb = (const char*)thl + r * 512;
        int swz = (r & 7) << 4;
        float* dst = th + (size_t)(b * 128 + r) * 256 + c0;
#pragma unroll
        for (int i = 0; i < 8; ++i) {
            bf16x8 sv = *(const bf16x8*)(rowb + (((c0 + i * 8) * 2) ^ swz));
            float4 v0, v1;
            v0.x = bf2f((unsigned short)sv[0]); v0.y = bf2f((unsigned short)sv[1]);
            v0.z = bf2f((unsigned short)sv[2]); v0.w = bf2f((unsigned short)sv[3]);
            v1.x = bf2f((unsigned short)sv[4]); v1.y = bf2f((unsigned short)sv[5]);
            v1.z = bf2f((unsigned short)sv[6]); v1.w = bf2f((unsigned short)sv[7]);
            *(float4*)(dst + i * 8) = v0;
            *(float4*)(dst + i * 8 + 4) = v1;
        }
    }
}

// ---------------------------------------------------------------------------
extern "C" void kernel_launch(void* const* d_in, const int* in_sizes, int n_in,
                              void* d_out, int out_size, void* d_ws, size_t ws_size,
                              hipStream_t stream) {
    const float* obs  = (const float*)d_in[0];
    const float* W1   = (const float*)d_in[1];
    const float* b1   = (const float*)d_in[2];
    const float* gg1  = (const float*)d_in[3];
    const float* be1  = (const float*)d_in[4];
    const float* W2   = (const float*)d_in[5];
    const float* b2   = (const float*)d_in[6];
    const float* gg2  = (const float*)d_in[7];
    const float* be2  = (const float*)d_in[8];
    const float* Wa1  = (const float*)d_in[9];
    const float* ba1  = (const float*)d_in[10];
    const float* Wa2  = (const float*)d_in[11];
    const float* ba2  = (const float*)d_in[12];
    const float* Wa3  = (const float*)d_in[13];
    const float* ba3  = (const float*)d_in[14];
    const float* Wf_ih = (const float*)d_in[15];
    const float* Wf_hh = (const float*)d_in[16];
    const float* bf_ih = (const float*)d_in[17];
    const float* bf_hh = (const float*)d_in[18];
    const float* Wb_ih = (const float*)d_in[19];
    const float* Wb_hh = (const float*)d_in[20];
    const float* bb_ih = (const float*)d_in[21];
    const float* bb_hh = (const float*)d_in[22];
    const float* W3   = (const float*)d_in[23];
    const float* b3   = (const float*)d_in[24];
    const float* gg3  = (const float*)d_in[25];
    const float* be3  = (const float*)d_in[26];
    const float* W4   = (const float*)d_in[27];
    const float* b4   = (const float*)d_in[28];
    const float* gg4  = (const float*)d_in[29];
    const float* be4  = (const float*)d_in[30];

    float* out     = (float*)d_out;
    float* out_acts = out;                   // 128*128*64
    float* out_C    = out + 1048576;         // 128*128*128
    float* out_ip   = out + 3145728;         // 16384
    float* out_ii   = out + 3162112;         // 16384
    float* out_nt   = out + 3178496;         // 128*128*256 (evolving thoughts)
    float* out_ot   = out + 7372800;         // 128*128*256 (old thoughts)

    float* ws    = (float*)d_ws;
    float* h1    = ws;                               // 4194304
    float* abuf  = ws + 4194304;                     // 2097152 (a1, later dot)
    float* a2buf = ws + 6291456;                     // 2097152 (a2, later act-pre)
    unsigned short* wihbf = (unsigned short*)(ws + 8388608);  // 262144 shorts
    float* biasz = ws + 8519680;                     // 1024
    unsigned short* whhbf = (unsigned short*)(ws + 8520704);  // 131072 shorts
    float* sqb   = ws + 8586240;                     // 16384
    int* idxb    = (int*)(ws + 8602624);             // 262144
    int* flagsb  = (int*)(ws + 8864768);             // 16384

    prep_kernel<<<512, 256, 0, stream>>>(Wf_ih, Wb_ih, Wf_hh, Wb_hh,
                                         bf_ih, bf_hh, bb_ih, bb_hh,
                                         wihbf, whhbf, biasz);

    // actor_1
    gemm64<<<dim3(4, 256), 256, 0, stream>>>(obs, W1, b1, h1, 16384, 256, 512, 0);
    ln256_kernel<<<4096, 256, 0, stream>>>(h1, h1, nullptr, gg1, be1, 1);
    gemm64<<<dim3(4, 256), 256, 0, stream>>>(h1, W2, b2, out_nt, 16384, 256, 256, 0);
    ln256_kernel<<<4096, 256, 0, stream>>>(out_nt, out_nt, out_ot, gg2, be2, 0);

    // attention unit
    gemm64<<<dim3(2, 256), 256, 0, stream>>>(out_nt, Wa1, ba1, abuf, 16384, 128, 256, 1);
    gemm64<<<dim3(2, 256), 256, 0, stream>>>(abuf, Wa2, ba2, a2buf, 16384, 128, 128, 1);
    attn_head_kernel<<<4096, 256, 0, stream>>>(a2buf, Wa3, ba3, out_ip, out_ii, flagsb);

    // pairwise distances + top-16
    dot_kernel<<<256, 256, 0, stream>>>(out_nt, abuf);
    sq_kernel<<<64, 256, 0, stream>>>(abuf, sqb);
    topk_kernel<<<4096, 256, 0, stream>>>(abuf, sqb, flagsb, out_C, idxb);

    // sequential communication chain (mutates out_nt), all-LDS agent loop
    chain_kernel<<<128, 512, 0, stream>>>(out_nt, whhbf, wihbf, biasz, idxb, flagsb);

    // actor_2
    gemm64<<<dim3(4, 256), 256, 0, stream>>>(out_nt, W3, b3, h1, 16384, 256, 256, 2);
    ln256_kernel<<<4096, 256, 0, stream>>>(h1, h1, nullptr, gg3, be3, 0);
    gemm64<<<dim3(1, 256), 256, 0, stream>>>(h1, W4, b4, a2buf, 16384, 64, 256, 0);
    ln64_tanh_kernel<<<4096, 256, 0, stream>>>(a2buf, out_acts, gg4, be4);
}

// Round 13
// 3615.131 us; speedup vs baseline: 1.2676x; 1.0411x over previous
//
#include <hip/hip_runtime.h>
#include <math.h>

typedef __attribute__((ext_vector_type(8))) short bf16x8;
typedef __attribute__((ext_vector_type(4))) float f32x4;

__device__ __forceinline__ unsigned short f2bf(float x) {
    unsigned int u = __float_as_uint(x);
    u += 0x7fffu + ((u >> 16) & 1u);
    return (unsigned short)(u >> 16);
}
__device__ __forceinline__ float bf2f(unsigned short b) {
    return __uint_as_float(((unsigned int)b) << 16);
}
// fast activations: v_exp_f32 + v_rcp_f32 (rel err ~1e-7, far below bf16 noise)
__device__ __forceinline__ float fsig(float z) {
    float e = __expf(-z);
    return __builtin_amdgcn_rcpf(1.f + e);
}
// tanh(x) = 2*sigmoid(2x) - 1  (5 instrs)
__device__ __forceinline__ float ftanh(float x) {
    float e = __expf(-2.f * x);
    float s = __builtin_amdgcn_rcpf(1.f + e);
    return fmaf(2.f, s, -1.f);
}
__device__ __forceinline__ bf16x8 pack8(float4 a, float4 b) {
    bf16x8 r;
    r[0] = (short)f2bf(a.x); r[1] = (short)f2bf(a.y);
    r[2] = (short)f2bf(a.z); r[3] = (short)f2bf(a.w);
    r[4] = (short)f2bf(b.x); r[5] = (short)f2bf(b.y);
    r[6] = (short)f2bf(b.z); r[7] = (short)f2bf(b.w);
    return r;
}

// ---------------------------------------------------------------------------
// prep: convert Wih and Whh to bf16, bias sums
// ---------------------------------------------------------------------------
__global__ void prep_kernel(const float* __restrict__ Wf_ih, const float* __restrict__ Wb_ih,
                            const float* __restrict__ Wf_hh, const float* __restrict__ Wb_hh,
                            const float* __restrict__ bf_ih, const float* __restrict__ bf_hh,
                            const float* __restrict__ bb_ih, const float* __restrict__ bb_hh,
                            unsigned short* __restrict__ wihbf,
                            unsigned short* __restrict__ whhbf,
                            float* __restrict__ biasz) {
    int i = blockIdx.x * 256 + threadIdx.x;   // grid 512*256 = 131072
    if (i < 131072) {
        wihbf[i]          = f2bf(Wf_ih[i]);
        wihbf[131072 + i] = f2bf(Wb_ih[i]);
    }
    if (i < 65536) {
        whhbf[i]         = f2bf(Wf_hh[i]);
        whhbf[65536 + i] = f2bf(Wb_hh[i]);
    }
    if (i < 512) {
        biasz[i]       = bf_ih[i] + bf_hh[i];
        biasz[512 + i] = bb_ih[i] + bb_hh[i];
    }
}

// ---------------------------------------------------------------------------
// generic fp32 GEMM  C[M,N] = A[M,K] @ B[K,N] + bias ; flags: 1=relu_out 2=relu_A
// ---------------------------------------------------------------------------
__global__ __launch_bounds__(256) void gemm64(const float* __restrict__ A,
                                              const float* __restrict__ Bm,
                                              const float* __restrict__ bias,
                                              float* __restrict__ C,
                                              int M, int N, int K, int flags) {
    __shared__ float As[16][68];
    __shared__ float Bs[16][68];
    const int t = threadIdx.x;
    const int row0 = blockIdx.y * 64, col0 = blockIdx.x * 64;
    const int tm = t >> 4, tn = t & 15;
    float acc[4][4] = {};
    for (int k0 = 0; k0 < K; k0 += 16) {
        {
            int r = t >> 2, kq = (t & 3) * 4;
            float4 v = *(const float4*)(A + (size_t)(row0 + r) * K + k0 + kq);
            if (flags & 2) {
                v.x = fmaxf(v.x, 0.f); v.y = fmaxf(v.y, 0.f);
                v.z = fmaxf(v.z, 0.f); v.w = fmaxf(v.w, 0.f);
            }
            As[kq + 0][r] = v.x; As[kq + 1][r] = v.y;
            As[kq + 2][r] = v.z; As[kq + 3][r] = v.w;
        }
        {
            int kk = t >> 4, nq = (t & 15) * 4;
            float4 v = *(const float4*)(Bm + (size_t)(k0 + kk) * N + col0 + nq);
            *(float4*)&Bs[kk][nq] = v;
        }
        __syncthreads();
#pragma unroll
        for (int kk = 0; kk < 16; ++kk) {
            float a[4], b[4];
#pragma unroll
            for (int i = 0; i < 4; ++i) a[i] = As[kk][tm * 4 + i];
#pragma unroll
            for (int j = 0; j < 4; ++j) b[j] = Bs[kk][tn * 4 + j];
#pragma unroll
            for (int i = 0; i < 4; ++i)
#pragma unroll
                for (int j = 0; j < 4; ++j) acc[i][j] = fmaf(a[i], b[j], acc[i][j]);
        }
        __syncthreads();
    }
#pragma unroll
    for (int i = 0; i < 4; ++i) {
#pragma unroll
        for (int j = 0; j < 4; ++j) {
            int col = col0 + tn * 4 + j;
            float v = acc[i][j] + (bias ? bias[col] : 0.f);
            if (flags & 1) v = fmaxf(v, 0.f);
            C[(size_t)(row0 + tm * 4 + i) * N + col] = v;
        }
    }
}

// ---------------------------------------------------------------------------
// LayerNorm over 256, one wave per row. Optional relu, optional dup output.
// ---------------------------------------------------------------------------
__global__ __launch_bounds__(256) void ln256_kernel(const float* __restrict__ X,
                                                    float* __restrict__ Y,
                                                    float* __restrict__ Y2,
                                                    const float* __restrict__ gam,
                                                    const float* __restrict__ bet,
                                                    int relu) {
#pragma clang fp contract(off)
    int row = blockIdx.x * 4 + (threadIdx.x >> 6);
    int l = threadIdx.x & 63;
    float4 x = *(const float4*)(X + (size_t)row * 256 + l * 4);
    float s = x.x + x.y + x.z + x.w;
#pragma unroll
    for (int d = 1; d < 64; d <<= 1) s += __shfl_xor(s, d);
    float mu = s * (1.f / 256.f);
    float d0 = x.x - mu, d1 = x.y - mu, d2 = x.z - mu, d3 = x.w - mu;
    float ss = d0 * d0 + d1 * d1 + d2 * d2 + d3 * d3;
#pragma unroll
    for (int d = 1; d < 64; d <<= 1) ss += __shfl_xor(ss, d);
    float var = ss * (1.f / 256.f);
    float sd = sqrtf(var + 1e-5f);
    float4 y;
    y.x = (d0 / sd) * gam[l * 4 + 0] + bet[l * 4 + 0];
    y.y = (d1 / sd) * gam[l * 4 + 1] + bet[l * 4 + 1];
    y.z = (d2 / sd) * gam[l * 4 + 2] + bet[l * 4 + 2];
    y.w = (d3 / sd) * gam[l * 4 + 3] + bet[l * 4 + 3];
    if (relu) {
        y.x = fmaxf(y.x, 0.f); y.y = fmaxf(y.y, 0.f);
        y.z = fmaxf(y.z, 0.f); y.w = fmaxf(y.w, 0.f);
    }
    *(float4*)(Y + (size_t)row * 256 + l * 4) = y;
    if (Y2) *(float4*)(Y2 + (size_t)row * 256 + l * 4) = y;
}

// LayerNorm over 64 + tanh, one wave per row
__global__ __launch_bounds__(256) void ln64_tanh_kernel(const float* __restrict__ X,
                                                        float* __restrict__ Y,
                                                        const float* __restrict__ gam,
                                                        const float* __restrict__ bet) {
#pragma clang fp contract(off)
    int row = blockIdx.x * 4 + (threadIdx.x >> 6);
    int l = threadIdx.x & 63;
    float x = X[(size_t)row * 64 + l];
    float s = x;
#pragma unroll
    for (int d = 1; d < 64; d <<= 1) s += __shfl_xor(s, d);
    float mu = s * (1.f / 64.f);
    float dx = x - mu;
    float ss = dx * dx;
#pragma unroll
    for (int d = 1; d < 64; d <<= 1) ss += __shfl_xor(ss, d);
    float var = ss * (1.f / 64.f);
    float sd = sqrtf(var + 1e-5f);
    float y = tanhf((dx / sd) * gam[l] + bet[l]);
    Y[(size_t)row * 64 + l] = y;
}

// ---------------------------------------------------------------------------
// attention head: p = sigmoid(a2 @ Wa3 + ba3), flags = p > 0.4
// ---------------------------------------------------------------------------
__global__ __launch_bounds__(256) void attn_head_kernel(const float* __restrict__ a2,
                                                        const float* __restrict__ Wa3,
                                                        const float* __restrict__ ba3,
                                                        float* __restrict__ outP,
                                                        float* __restrict__ outInit,
                                                        int* __restrict__ flags) {
#pragma clang fp contract(off)
    int row = blockIdx.x * 4 + (threadIdx.x >> 6);
    int l = threadIdx.x & 63;
    float s = a2[(size_t)row * 128 + l] * Wa3[l] + a2[(size_t)row * 128 + 64 + l] * Wa3[64 + l];
#pragma unroll
    for (int d = 1; d < 64; d <<= 1) s += __shfl_xor(s, d);
    s += ba3[0];
    float p = 1.f / (1.f + expf(-s));
    if (l == 0) {
        outP[row] = p;
        int f = (p > 0.4f) ? 1 : 0;
        outInit[row] = f ? 1.f : 0.f;
        flags[row] = f;
    }
}

// ---------------------------------------------------------------------------
// batched dot: dot[b] = th_b @ th_b^T   (128x128, K=256); 2 blocks per batch
// ---------------------------------------------------------------------------
__global__ __launch_bounds__(256) void dot_kernel(const float* __restrict__ th,
                                                  float* __restrict__ dotm) {
    __shared__ float As[16][68];
    __shared__ float Bs[16][132];
    const int b = blockIdx.x >> 1, half = blockIdx.x & 1;
    const int t = threadIdx.x;
    const int tm = t >> 4, tn = t & 15;
    float acc[4][8] = {};
    const float* base = th + (size_t)b * 128 * 256;
    for (int k0 = 0; k0 < 256; k0 += 16) {
        {
            int r = t >> 2, kq = (t & 3) * 4;
            float4 v = *(const float4*)(base + (size_t)(half * 64 + r) * 256 + k0 + kq);
            As[kq + 0][r] = v.x; As[kq + 1][r] = v.y;
            As[kq + 2][r] = v.z; As[kq + 3][r] = v.w;
        }
        {
            int n = t >> 1, kq = (t & 1) * 8;
            const float* src = base + (size_t)n * 256 + k0 + kq;
            float4 v0 = *(const float4*)src;
            float4 v1 = *(const float4*)(src + 4);
            Bs[kq + 0][n] = v0.x; Bs[kq + 1][n] = v0.y;
            Bs[kq + 2][n] = v0.z; Bs[kq + 3][n] = v0.w;
            Bs[kq + 4][n] = v1.x; Bs[kq + 5][n] = v1.y;
            Bs[kq + 6][n] = v1.z; Bs[kq + 7][n] = v1.w;
        }
        __syncthreads();
#pragma unroll
        for (int kk = 0; kk < 16; ++kk) {
            float a[4], bb[8];
#pragma unroll
            for (int i = 0; i < 4; ++i) a[i] = As[kk][tm * 4 + i];
#pragma unroll
            for (int j = 0; j < 8; ++j) bb[j] = Bs[kk][tn * 8 + j];
#pragma unroll
            for (int i = 0; i < 4; ++i)
#pragma unroll
                for (int j = 0; j < 8; ++j) acc[i][j] = fmaf(a[i], bb[j], acc[i][j]);
        }
        __syncthreads();
    }
#pragma unroll
    for (int i = 0; i < 4; ++i)
#pragma unroll
        for (int j = 0; j < 8; ++j)
            dotm[(size_t)b * 16384 + (size_t)(half * 64 + tm * 4 + i) * 128 + tn * 8 + j] = acc[i][j];
}

__global__ void sq_kernel(const float* __restrict__ dotm, float* __restrict__ sq) {
    int i = blockIdx.x * 256 + threadIdx.x;   // 64 blocks
    int b = i >> 7, n = i & 127;
    sq[i] = dotm[(size_t)b * 16384 + (size_t)n * 129];
}

// ---------------------------------------------------------------------------
// top-16 smallest distances per row (ties -> lower index), write C + idx
// ---------------------------------------------------------------------------
__global__ __launch_bounds__(256) void topk_kernel(const float* __restrict__ dotm,
                                                   const float* __restrict__ sq,
                                                   const int* __restrict__ flags,
                                                   float* __restrict__ outC,
                                                   int* __restrict__ idxb) {
#pragma clang fp contract(off)
    int row = blockIdx.x * 4 + (threadIdx.x >> 6);
    int l = threadIdx.x & 63;
    int b = row >> 7;
    const float* drow = dotm + (size_t)row * 128;
    float sqi = sq[row];
    float t0 = 2.f * drow[l];
    float v0 = sq[b * 128 + l] - t0; v0 = v0 + sqi;
    float t1 = 2.f * drow[64 + l];
    float v1 = sq[b * 128 + 64 + l] - t1; v1 = v1 + sqi;

    unsigned long long mlo = 0ull, mhi = 0ull;
#pragma unroll 1
    for (int n = 0; n < 16; ++n) {
        float bv = v0; int bi = l;
        if (v1 < bv) { bv = v1; bi = 64 + l; }
#pragma unroll
        for (int d = 1; d < 64; d <<= 1) {
            float ov = __shfl_xor(bv, d);
            int oi = __shfl_xor(bi, d);
            if (ov < bv || (ov == bv && oi < bi)) { bv = ov; bi = oi; }
        }
        if (bi < 64) mlo |= (1ull << bi); else mhi |= (1ull << (bi - 64));
        if (l == bi) v0 = __builtin_inff();
        if (64 + l == bi) v1 = __builtin_inff();
    }
    float fl = (flags[row] != 0) ? 1.f : 0.f;
    outC[(size_t)row * 128 + l]      = fl * (((mlo >> l) & 1ull) ? 1.f : 0.f);
    outC[(size_t)row * 128 + 64 + l] = fl * (((mhi >> l) & 1ull) ? 1.f : 0.f);
    if (l < 16) {
        int cnt = 0, found = -1;
        for (int jj = 0; jj < 128; ++jj) {
            bool bit = (jj < 64) ? ((mlo >> jj) & 1ull) : ((mhi >> (jj - 64)) & 1ull);
            if (bit) { if (cnt == l) { found = jj; break; } ++cnt; }
        }
        idxb[(size_t)row * 16 + l] = found;
    }
}

// ---------------------------------------------------------------------------
// THE CHAIN (R7 configuration — best measured: 3331 us chain, 3612 total).
// One 512-thread block per batch, 8 waves (4 fwd, 4 bwd), 2/SIMD. Lane lr
// of wave wd owns ADJACENT units {wd*32+2lr, +1} (gate row = G*128 + wd*32
// + 2lr + hf) -> one ds_write_b32 per step. h history lives in
// hsnap[2][18][128] (rows 0/17 = permanent zero initial state): the step
// reads prev-member h from row m (fwd) / m+2 (bwd) and writes row m+1 — no
// ping-pong, no per-agent zeroing. Whh resident: 32 bf16x8 = 128 VGPRs.
// Per-step LDS: 4x b128 (h) + 1x b128 (xg prefetch) reads + 1x b32 write,
// ONE barrier.
// ---------------------------------------------------------------------------
__global__ __launch_bounds__(512, 2) void chain_kernel(float* __restrict__ th,
                                                       const unsigned short* __restrict__ whhbf,
                                                       const unsigned short* __restrict__ wihbf,
                                                       const float* __restrict__ biasz,
                                                       const int* __restrict__ idxb,
                                                       const int* __restrict__ flags) {
    const int b = blockIdx.x;
    const int t = threadIdx.x;
    const int l = t & 63, lr = l & 15, lg = l >> 4;
    const int w = t >> 6, dir = w >> 2, wd = w & 3;

    __shared__ __align__(16) unsigned short thl[128 * 256];        // 64 KB swizzled bf16
    __shared__ __align__(16) unsigned short xgs2[2 * 4 * 16 * 16 * 8]; // 32 KB [dir][wd][m][lr][8]
    __shared__ __align__(16) unsigned short hsnap[2][18][128];     // 9 KB h history + 0-rows
    __shared__ int idxl[2048];                                     // 8 KB
    __shared__ int flg[128];

    // ---- load th slice -> bf16 LDS (swizzled); row r = t>>2, 64 floats each
    {
        int r = t >> 2, c0 = (t & 3) * 64;
        const float* src = th + (size_t)(b * 128 + r) * 256 + c0;
        char* rowb = (char*)thl + r * 512;
        int swz = (r & 7) << 4;
#pragma unroll
        for (int i = 0; i < 8; ++i) {
            float4 v0 = *(const float4*)(src + i * 8);
            float4 v1 = *(const float4*)(src + i * 8 + 4);
            *(bf16x8*)(rowb + (((c0 + i * 8) * 2) ^ swz)) = pack8(v0, v1);
        }
    }
    if (t < 128) flg[t] = flags[b * 128 + t];
    if (t < 256) {   // permanent zero boundary rows (initial LSTM state)
        int d2 = t >> 7, j = t & 127;
        hsnap[d2][0][j] = 0;
        hsnap[d2][17][j] = 0;
    }
#pragma unroll
    for (int c = 0; c < 4; ++c) idxl[t + c * 512] = idxb[(size_t)b * 2048 + c * 512 + t];

    // ---- resident Whh bf16 B-fragments: 32 frags = 128 regs
    bf16x8 wf[4][2][4];
    {
        const unsigned short* whh = whhbf + (size_t)dir * 65536;
#pragma unroll
        for (int G = 0; G < 4; ++G)
#pragma unroll
            for (int hf = 0; hf < 2; ++hf) {
                int gate = G * 128 + wd * 32 + 2 * lr + hf;
#pragma unroll
                for (int kc = 0; kc < 4; ++kc)
                    wf[G][hf][kc] = *(const bf16x8*)(whh + (size_t)gate * 128 + kc * 32 + lg * 8);
            }
    }
    const unsigned short* wih = wihbf + (size_t)dir * 131072;
    float bzr[8];
#pragma unroll
    for (int tt = 0; tt < 8; ++tt)
        bzr[tt] = biasz[dir * 512 + (tt >> 1) * 128 + wd * 32 + 2 * lr + (tt & 1)];
    __syncthreads();

    const int xgbase = ((dir * 4 + wd) * 16) * 16 * 8;   // this wave's xg slab

    for (int ag = 0; ag < 128; ++ag) {
        if (!flg[ag]) continue;
        const int gi_lr = idxl[ag * 16 + lr];

        // xg: A rows = 16 members (thl rows gi), B cols = this wave's 8 gate
        // tiles tt=(G,hf); gate = G*128 + wd*32 + 2*lr + hf
        {
            f32x4 xa[8];
#pragma unroll
            for (int tt = 0; tt < 8; ++tt) xa[tt] = (f32x4){0.f, 0.f, 0.f, 0.f};
            const char* arow = (const char*)thl + gi_lr * 512;
            const int aswz = (gi_lr & 7) << 4;
#pragma unroll
            for (int kc = 0; kc < 8; ++kc) {
                bf16x8 af = *(const bf16x8*)(arow + ((kc * 64 + lg * 16) ^ aswz));
#pragma unroll
                for (int tt = 0; tt < 8; ++tt) {
                    const unsigned short* wb =
                        wih + (size_t)((tt >> 1) * 128 + wd * 32 + 2 * lr + (tt & 1)) * 256 +
                        kc * 32 + lg * 8;
                    xa[tt] = __builtin_amdgcn_mfma_f32_16x16x32_bf16(
                        af, *(const bf16x8*)wb, xa[tt], 0, 0, 0);
                }
            }
            // store transposed: [dir][wd][m][lr][8 gates] -> one b128 per (m,lr)
#pragma unroll
            for (int r = 0; r < 4; ++r) {
                bf16x8 pk;
#pragma unroll
                for (int tt = 0; tt < 8; ++tt) pk[tt] = (short)f2bf(xa[tt][r] + bzr[tt]);
                int m = lg * 4 + r;
                *(bf16x8*)&xgs2[xgbase + (m * 16 + lr) * 8] = pk;
            }
        }
        __syncthreads();   // xgs2 ready

        // preload xg for first step
        bf16x8 xpn = *(const bf16x8*)&xgs2[xgbase + ((dir ? 15 : 0) * 16 + lr) * 8];

        // 16-step recurrence: 5x ds_read_b128 + 16 MFMA + acts + 1x ds_write_b32
        float cst0 = 0.f, cst1 = 0.f;
        for (int s = 0; s < 16; ++s) {
            const int m = dir ? (15 - s) : s;
            const int rprev = dir ? (m + 2) : m;
            f32x4 acc[4][2];
#pragma unroll
            for (int G = 0; G < 4; ++G) {
                acc[G][0] = (f32x4){0.f, 0.f, 0.f, 0.f};
                acc[G][1] = (f32x4){0.f, 0.f, 0.f, 0.f};
            }
#pragma unroll
            for (int kc = 0; kc < 4; ++kc) {
                bf16x8 ha = *(const bf16x8*)(&hsnap[dir][rprev][kc * 32 + lg * 8]);
#pragma unroll
                for (int G = 0; G < 4; ++G) {
                    acc[G][0] = __builtin_amdgcn_mfma_f32_16x16x32_bf16(
                        ha, wf[G][0][kc], acc[G][0], 0, 0, 0);
                    acc[G][1] = __builtin_amdgcn_mfma_f32_16x16x32_bf16(
                        ha, wf[G][1][kc], acc[G][1], 0, 0, 0);
                }
            }
            bf16x8 xp = xpn;
            float zi0 = acc[0][0][0] + bf2f((unsigned short)xp[0]);
            float zi1 = acc[0][1][0] + bf2f((unsigned short)xp[1]);
            float zf0 = acc[1][0][0] + bf2f((unsigned short)xp[2]);
            float zf1 = acc[1][1][0] + bf2f((unsigned short)xp[3]);
            float zg0 = acc[2][0][0] + bf2f((unsigned short)xp[4]);
            float zg1 = acc[2][1][0] + bf2f((unsigned short)xp[5]);
            float zo0 = acc[3][0][0] + bf2f((unsigned short)xp[6]);
            float zo1 = acc[3][1][0] + bf2f((unsigned short)xp[7]);
            float i0 = fsig(zi0), f0 = fsig(zf0), g0 = ftanh(zg0), o0 = fsig(zo0);
            cst0 = f0 * cst0 + i0 * g0;
            float h0 = o0 * ftanh(cst0);
            float i1 = fsig(zi1), f1 = fsig(zf1), g1 = ftanh(zg1), o1 = fsig(zo1);
            cst1 = f1 * cst1 + i1 * g1;
            float h1 = o1 * ftanh(cst1);
            if (lg == 0) {
                unsigned int hw = (unsigned int)f2bf(h0) | ((unsigned int)f2bf(h1) << 16);
                *(unsigned int*)&hsnap[dir][m + 1][wd * 32 + 2 * lr] = hw;
            }
            // prefetch next step's xg (hides ds latency under barrier wait)
            if (s < 15) {
                int mn = dir ? (14 - s) : (s + 1);
                xpn = *(const bf16x8*)&xgs2[xgbase + (mn * 16 + lr) * 8];
            }
            __syncthreads();
        }

        // bulk scatter hsnap -> thl (swizzled), 512 threads cover 2*16*128
        {
            int d2 = t >> 8, m = (t >> 4) & 15, c8 = (t & 15) * 8;
            bf16x8 v = *(const bf16x8*)&hsnap[d2][m + 1][c8];
            int row = idxl[ag * 16 + m];
            *(bf16x8*)((char*)thl + row * 512 + (((d2 * 128 + c8) * 2) ^ ((row & 7) << 4))) = v;
        }
        __syncthreads();
    }

    // ---- write back the whole slice (un-swizzle, bf16 -> fp32)
    {
        int r = t >> 2, c0 = (t & 3) * 64;
        const char* rowb = (const char*)thl + r * 512;
        int swz = (r & 7) << 4;
        float* dst = th + (size_t)(b * 128 + r) * 256 + c0;
#pragma unroll
        for (int i = 0; i < 8; ++i) {
            bf16x8 sv = *(const bf16x8*)(rowb + (((c0 + i * 8) * 2) ^ swz));
            float4 v0, v1;
            v0.x = bf2f((unsigned short)sv[0]); v0.y = bf2f((unsigned short)sv[1]);
            v0.z = bf2f((unsigned short)sv[2]); v0.w = bf2f((unsigned short)sv[3]);
            v1.x = bf2f((unsigned short)sv[4]); v1.y = bf2f((unsigned short)sv[5]);
            v1.z = bf2f((unsigned short)sv[6]); v1.w = bf2f((unsigned short)sv[7]);
            *(float4*)(dst + i * 8) = v0;
            *(float4*)(dst + i * 8 + 4) = v1;
        }
    }
}

// ---------------------------------------------------------------------------
extern "C" void kernel_launch(void* const* d_in, const int* in_sizes, int n_in,
                              void* d_out, int out_size, void* d_ws, size_t ws_size,
                              hipStream_t stream) {
    const float* obs  = (const float*)d_in[0];
    const float* W1   = (const float*)d_in[1];
    const float* b1   = (const float*)d_in[2];
    const float* gg1  = (const float*)d_in[3];
    const float* be1  = (const float*)d_in[4];
    const float* W2   = (const float*)d_in[5];
    const float* b2   = (const float*)d_in[6];
    const float* gg2  = (const float*)d_in[7];
    const float* be2  = (const float*)d_in[8];
    const float* Wa1  = (const float*)d_in[9];
    const float* ba1  = (const float*)d_in[10];
    const float* Wa2  = (const float*)d_in[11];
    const float* ba2  = (const float*)d_in[12];
    const float* Wa3  = (const float*)d_in[13];
    const float* ba3  = (const float*)d_in[14];
    const float* Wf_ih = (const float*)d_in[15];
    const float* Wf_hh = (const float*)d_in[16];
    const float* bf_ih = (const float*)d_in[17];
    const float* bf_hh = (const float*)d_in[18];
    const float* Wb_ih = (const float*)d_in[19];
    const float* Wb_hh = (const float*)d_in[20];
    const float* bb_ih = (const float*)d_in[21];
    const float* bb_hh = (const float*)d_in[22];
    const float* W3   = (const float*)d_in[23];
    const float* b3   = (const float*)d_in[24];
    const float* gg3  = (const float*)d_in[25];
    const float* be3  = (const float*)d_in[26];
    const float* W4   = (const float*)d_in[27];
    const float* b4   = (const float*)d_in[28];
    const float* gg4  = (const float*)d_in[29];
    const float* be4  = (const float*)d_in[30];

    float* out     = (float*)d_out;
    float* out_acts = out;                   // 128*128*64
    float* out_C    = out + 1048576;         // 128*128*128
    float* out_ip   = out + 3145728;         // 16384
    float* out_ii   = out + 3162112;         // 16384
    float* out_nt   = out + 3178496;         // 128*128*256 (evolving thoughts)
    float* out_ot   = out + 7372800;         // 128*128*256 (old thoughts)

    float* ws    = (float*)d_ws;
    float* h1    = ws;                               // 4194304
    float* abuf  = ws + 4194304;                     // 2097152 (a1, later dot)
    float* a2buf = ws + 6291456;                     // 2097152 (a2, later act-pre)
    unsigned short* wihbf = (unsigned short*)(ws + 8388608);  // 262144 shorts
    float* biasz = ws + 8519680;                     // 1024
    unsigned short* whhbf = (unsigned short*)(ws + 8520704);  // 131072 shorts
    float* sqb   = ws + 8586240;                     // 16384
    int* idxb    = (int*)(ws + 8602624);             // 262144
    int* flagsb  = (int*)(ws + 8864768);             // 16384

    prep_kernel<<<512, 256, 0, stream>>>(Wf_ih, Wb_ih, Wf_hh, Wb_hh,
                                         bf_ih, bf_hh, bb_ih, bb_hh,
                                         wihbf, whhbf, biasz);

    // actor_1
    gemm64<<<dim3(4, 256), 256, 0, stream>>>(obs, W1, b1, h1, 16384, 256, 512, 0);
    ln256_kernel<<<4096, 256, 0, stream>>>(h1, h1, nullptr, gg1, be1, 1);
    gemm64<<<dim3(4, 256), 256, 0, stream>>>(h1, W2, b2, out_nt, 16384, 256, 256, 0);
    ln256_kernel<<<4096, 256, 0, stream>>>(out_nt, out_nt, out_ot, gg2, be2, 0);

    // attention unit
    gemm64<<<dim3(2, 256), 256, 0, stream>>>(out_nt, Wa1, ba1, abuf, 16384, 128, 256, 1);
    gemm64<<<dim3(2, 256), 256, 0, stream>>>(abuf, Wa2, ba2, a2buf, 16384, 128, 128, 1);
    attn_head_kernel<<<4096, 256, 0, stream>>>(a2buf, Wa3, ba3, out_ip, out_ii, flagsb);

    // pairwise distances + top-16
    dot_kernel<<<256, 256, 0, stream>>>(out_nt, abuf);
    sq_kernel<<<64, 256, 0, stream>>>(abuf, sqb);
    topk_kernel<<<4096, 256, 0, stream>>>(abuf, sqb, flagsb, out_C, idxb);

    // sequential communication chain (mutates out_nt), all-LDS agent loop
    chain_kernel<<<128, 512, 0, stream>>>(out_nt, whhbf, wihbf, biasz, idxb, flagsb);

    // actor_2
    gemm64<<<dim3(4, 256), 256, 0, stream>>>(out_nt, W3, b3, h1, 16384, 256, 256, 2);
    ln256_kernel<<<4096, 256, 0, stream>>>(h1, h1, nullptr, gg3, be3, 0);
    gemm64<<<dim3(1, 256), 256, 0, stream>>>(h1, W4, b4, a2buf, 16384, 64, 256, 0);
    ln64_tanh_kernel<<<4096, 256, 0, stream>>>(a2buf, out_acts, gg4, be4);
}